// Round 1
// baseline (426.473 us; speedup 1.0000x reference)
//
#include <hip/hip_runtime.h>

typedef __bf16 bf16;
typedef __bf16 bf16x8 __attribute__((ext_vector_type(8)));
typedef __bf16 bf16x4 __attribute__((ext_vector_type(4)));
typedef float f32x4 __attribute__((ext_vector_type(4)));

#define MFMA16(a, b, c) __builtin_amdgcn_mfma_f32_16x16x32_bf16(a, b, c, 0, 0, 0)

// ---------------- convert x (f32 -> bf16) ----------------
__global__ __launch_bounds__(256) void cvt_x_kernel(const float* __restrict__ x,
                                                    bf16* __restrict__ xb) {
  const long i = (long)blockIdx.x * 256 + threadIdx.x;  // one float4 per thread
  const float4 v = ((const float4*)x)[i];
  bf16x4 o4;
  o4.x = (bf16)v.x; o4.y = (bf16)v.y; o4.z = (bf16)v.z; o4.w = (bf16)v.w;
  ((bf16x4*)xb)[i] = o4;
}

// ---------------- transpose-convert [wq|wk|wv] (K x N) -> (N x K) bf16 ----------------
__global__ __launch_bounds__(256) void wqkv_trans_kernel(const float* __restrict__ wq,
                                                         const float* __restrict__ wk,
                                                         const float* __restrict__ wv,
                                                         bf16* __restrict__ dst) {
  __shared__ float tile[32][33];
  const int k0 = blockIdx.x * 32, n0 = blockIdx.y * 32;
  const float* src; int col, srcN;
  if (n0 < 2048)      { src = wq; col = n0;        srcN = 2048; }
  else if (n0 < 3072) { src = wk; col = n0 - 2048; srcN = 1024; }
  else                { src = wv; col = n0 - 3072; srcN = 1024; }
  const int tx = threadIdx.x, ty = threadIdx.y;  // 32 x 8
#pragma unroll
  for (int i = 0; i < 4; ++i)
    tile[ty + i * 8][tx] = src[(long)(k0 + ty + i * 8) * srcN + col + tx];
  __syncthreads();
#pragma unroll
  for (int i = 0; i < 4; ++i)
    dst[(long)(n0 + ty + i * 8) * 2560 + k0 + tx] = (bf16)tile[tx][ty + i * 8];
}

// ---------------- transpose-convert wo (2048 x 2560) -> (2560 x 2048) bf16 ----------------
__global__ __launch_bounds__(256) void wo_trans_kernel(const float* __restrict__ wo,
                                                       bf16* __restrict__ dst) {
  __shared__ float tile[32][33];
  const int k0 = blockIdx.x * 32, n0 = blockIdx.y * 32;  // k over 2048 rows, n over 2560 cols
  const int tx = threadIdx.x, ty = threadIdx.y;
#pragma unroll
  for (int i = 0; i < 4; ++i)
    tile[ty + i * 8][tx] = wo[(long)(k0 + ty + i * 8) * 2560 + n0 + tx];
  __syncthreads();
#pragma unroll
  for (int i = 0; i < 4; ++i)
    dst[(long)(n0 + ty + i * 8) * 2048 + k0 + tx] = (bf16)tile[tx][ty + i * 8];
}

// ---------------- transpose new V slice (f32, [s][d]) -> vt bf16 [d][s] ----------------
__global__ __launch_bounds__(256) void v_trans_kernel(const float* __restrict__ vout,
                                                      const int* __restrict__ p_ci,
                                                      bf16* __restrict__ vt) {
  __shared__ float tile[32][33];
  const int s0 = blockIdx.x * 32, d0 = blockIdx.y * 32, bk = blockIdx.z;  // bk = b*4+kvh
  const int ci = *p_ci;
  const int tx = threadIdx.x, ty = threadIdx.y;
  const float* src = vout + ((long)bk * 4096 + ci) * 256;
#pragma unroll
  for (int i = 0; i < 4; ++i)
    tile[ty + i * 8][tx] = src[(long)(s0 + ty + i * 8) * 256 + d0 + tx];
  __syncthreads();
  bf16* dstb = vt + ((long)bk * 256 + d0) * 1024 + s0;
#pragma unroll
  for (int i = 0; i < 4; ++i)
    dstb[(long)(ty + i * 8) * 1024 + tx] = (bf16)tile[tx][ty + i * 8];
}

// ---------------- bf16 MFMA GEMM: C(f32, MxN) = A(MxK) * BT(NxK)^T ----------------
// BM=BN=128, BK=32, 256 threads = 4 waves, each wave a 64x64 quadrant (4x4 16x16 subtiles)
template <int K, int N>
__global__ __launch_bounds__(256) void gemm_kernel(const bf16* __restrict__ A,
                                                   const bf16* __restrict__ BT,
                                                   float* __restrict__ C) {
  __shared__ bf16 As[128 * 40];  // +8 pad: row stride 80B -> 2-way bank alias (free)
  __shared__ bf16 Bs[128 * 40];
  const int bm = blockIdx.x, bn = blockIdx.y;
  const int tid = threadIdx.x;
  const int wave = tid >> 6, lane = tid & 63;
  const int quad = lane >> 4, l16 = lane & 15;
  const int wm = (wave & 1) * 64, wn = (wave >> 1) * 64;
  f32x4 acc[4][4] = {};
  const int r0 = tid >> 2, o0 = (tid & 3) * 8;  // chunk 0 (512 chunks of 8 bf16)
  const int r1 = r0 + 64;                       // chunk 1
  const bf16* Ag = A + (long)(bm * 128) * K;
  const bf16* Bg = BT + (long)(bn * 128) * K;
  for (int k0 = 0; k0 < K; k0 += 32) {
    uint4 a0 = *(const uint4*)(Ag + (long)r0 * K + k0 + o0);
    uint4 a1 = *(const uint4*)(Ag + (long)r1 * K + k0 + o0);
    uint4 b0 = *(const uint4*)(Bg + (long)r0 * K + k0 + o0);
    uint4 b1 = *(const uint4*)(Bg + (long)r1 * K + k0 + o0);
    __syncthreads();  // previous iter's ds_reads done before overwrite
    *(uint4*)(As + r0 * 40 + o0) = a0;
    *(uint4*)(As + r1 * 40 + o0) = a1;
    *(uint4*)(Bs + r0 * 40 + o0) = b0;
    *(uint4*)(Bs + r1 * 40 + o0) = b1;
    __syncthreads();
    bf16x8 af[4], bfr[4];
#pragma unroll
    for (int mi = 0; mi < 4; ++mi)
      af[mi] = *(const bf16x8*)(As + (wm + mi * 16 + l16) * 40 + quad * 8);
#pragma unroll
    for (int ni = 0; ni < 4; ++ni)
      bfr[ni] = *(const bf16x8*)(Bs + (wn + ni * 16 + l16) * 40 + quad * 8);
#pragma unroll
    for (int mi = 0; mi < 4; ++mi)
#pragma unroll
      for (int ni = 0; ni < 4; ++ni)
        acc[mi][ni] = MFMA16(af[mi], bfr[ni], acc[mi][ni]);
  }
  const int crow = bm * 128 + wm + quad * 4;
  const int ccol = bn * 128 + wn + l16;
#pragma unroll
  for (int mi = 0; mi < 4; ++mi)
#pragma unroll
    for (int ni = 0; ni < 4; ++ni)
#pragma unroll
      for (int r = 0; r < 4; ++r)
        C[(long)(crow + mi * 16 + r) * N + ccol + ni * 16] = acc[mi][ni][r];
}

// ---------------- RMSNorm + RoPE + cache scatter ----------------
// grid (2048 tokens, 16 slots): slot 0..7 = q head, 8..11 = k head, 12..15 = v head
__global__ __launch_bounds__(256) void normrope_kernel(
    const float* __restrict__ qkv, const float* __restrict__ qw,
    const float* __restrict__ kw, const int* __restrict__ p_pos,
    const int* __restrict__ p_ci, float* __restrict__ kout,
    float* __restrict__ vout, bf16* __restrict__ q_bf, bf16* __restrict__ k_bf) {
  const int bt = blockIdx.x, slot = blockIdx.y;
  const int t = bt & 1023, b = bt >> 10;
  const int d = threadIdx.x;
  const float val = qkv[(long)bt * 4096 + slot * 256 + d];
  const int ci = *p_ci;
  if (slot >= 12) {  // v: plain scatter into cache (uniform branch per block)
    vout[((long)(b * 4 + (slot - 12)) * 4096 + ci + t) * 256 + d] = val;
    return;
  }
  __shared__ float red[4];
  __shared__ float rowbuf[256];
  float ss = val * val;
#pragma unroll
  for (int i = 1; i < 64; i <<= 1) ss += __shfl_xor(ss, i);
  if ((d & 63) == 0) red[d >> 6] = ss;
  __syncthreads();
  const float tot = red[0] + red[1] + red[2] + red[3];
  const float rstd = rsqrtf(tot * (1.0f / 256.0f) + 1e-6f);
  const bool isq = slot < 8;
  const float wv = isq ? qw[d] : kw[d];
  const float nv = val * rstd * (1.0f + wv);
  rowbuf[d] = nv;
  __syncthreads();
  const int e = d & 127;
  // inv_freq = 10000^(-2e/256) = 2^(-e * log2(10000)/128)
  const float inv_freq = exp2f((float)e * -0.10381025296522976f);
  const float ang = (float)(*p_pos + t) * inv_freq;
  float sn, cs;
  sincosf(ang, &sn, &cs);
  float outv;
  if (d < 128) outv = nv * cs - rowbuf[d + 128] * sn;
  else         outv = nv * cs + rowbuf[d - 128] * sn;
  if (isq) {
    q_bf[((long)(b * 8 + slot) * 1024 + t) * 256 + d] = (bf16)outv;
  } else {
    const int kh = slot - 8;
    kout[((long)(b * 4 + kh) * 4096 + ci + t) * 256 + d] = outv;  // f32 cache out
    k_bf[((long)(b * 4 + kh) * 1024 + t) * 256 + d] = (bf16)outv;
  }
}

// ---------------- flash attention over the T new tokens (all valid, no causal mask) ----
// grid (16 q-tiles, 8 heads, 2 batch); 256 thr = 4 waves; wave owns 16 query rows.
__global__ __launch_bounds__(256) void attn_kernel(const bf16* __restrict__ q_bf,
                                                   const bf16* __restrict__ k_bf,
                                                   const bf16* __restrict__ vt_bf,
                                                   bf16* __restrict__ attn) {
  __shared__ bf16 Ks[64 * 264];   // [s][d], +8 pad
  __shared__ bf16 Vs[256 * 72];   // [d][s], +8 pad
  __shared__ bf16 Ps[64 * 72];    // [t][s], +8 pad
  const int qt = blockIdx.x, h = blockIdx.y, b = blockIdx.z;
  const int kvh = h >> 1;
  const int tid = threadIdx.x;
  const int wave = tid >> 6, lane = tid & 63, quad = lane >> 4, l16 = lane & 15;
  // Q fragments resident in registers: A[m=l16][k=quad*8+j], 8 k-steps of 32
  bf16x8 qf[8];
  const bf16* qg =
      q_bf + ((long)(b * 8 + h) * 1024 + qt * 64 + wave * 16 + l16) * 256 + quad * 8;
#pragma unroll
  for (int i = 0; i < 8; ++i) qf[i] = *(const bf16x8*)(qg + i * 32);
  f32x4 o[16] = {};
  float m_r[4] = {-1e30f, -1e30f, -1e30f, -1e30f};
  float l_r[4] = {0.f, 0.f, 0.f, 0.f};
  const float sfac = 0.0625f * 1.44269504088896f;  // SCALE * log2(e)
  const bf16* kgb = k_bf + (long)(b * 4 + kvh) * 1024 * 256;
  const bf16* vgb = vt_bf + (long)(b * 4 + kvh) * 256 * 1024;
  for (int st = 0; st < 16; ++st) {
    __syncthreads();  // previous iter's PV reads done
#pragma unroll
    for (int i = 0; i < 8; ++i) {  // stage K tile 64x256
      int c = tid + i * 256;
      *(uint4*)(Ks + (c >> 5) * 264 + (c & 31) * 8) =
          *(const uint4*)(kgb + (long)(st * 64 + (c >> 5)) * 256 + (c & 31) * 8);
    }
#pragma unroll
    for (int i = 0; i < 8; ++i) {  // stage V^T tile 256x64
      int c = tid + i * 256;
      *(uint4*)(Vs + (c >> 3) * 72 + (c & 7) * 8) =
          *(const uint4*)(vgb + (long)(c >> 3) * 1024 + st * 64 + (c & 7) * 8);
    }
    __syncthreads();
    // S = Q K^T : wave rows (16) x 64 cols
    f32x4 sacc[4] = {};
#pragma unroll
    for (int kk = 0; kk < 8; ++kk) {
#pragma unroll
      for (int ni = 0; ni < 4; ++ni) {
        bf16x8 kf = *(const bf16x8*)(Ks + (ni * 16 + l16) * 264 + kk * 32 + quad * 8);
        sacc[ni] = MFMA16(qf[kk], kf, sacc[ni]);
      }
    }
    // online softmax in exp2 domain; row = quad*4 + r, replicated over 16 lanes of quad
    float alpha_r[4];
#pragma unroll
    for (int r = 0; r < 4; ++r) {
      float s0 = sacc[0][r] * sfac, s1 = sacc[1][r] * sfac;
      float s2 = sacc[2][r] * sfac, s3 = sacc[3][r] * sfac;
      float mx = fmaxf(fmaxf(s0, s1), fmaxf(s2, s3));
#pragma unroll
      for (int dd = 1; dd < 16; dd <<= 1) mx = fmaxf(mx, __shfl_xor(mx, dd));
      float mnew = fmaxf(m_r[r], mx);
      float al = exp2f(m_r[r] - mnew);
      m_r[r] = mnew;
      alpha_r[r] = al;
      float p0 = exp2f(s0 - mnew), p1 = exp2f(s1 - mnew);
      float p2 = exp2f(s2 - mnew), p3 = exp2f(s3 - mnew);
      float rs = p0 + p1 + p2 + p3;
#pragma unroll
      for (int dd = 1; dd < 16; dd <<= 1) rs += __shfl_xor(rs, dd);
      l_r[r] = l_r[r] * al + rs;
      const int prow = (wave * 16 + quad * 4 + r) * 72;
      Ps[prow + l16] = (bf16)p0;
      Ps[prow + 16 + l16] = (bf16)p1;
      Ps[prow + 32 + l16] = (bf16)p2;
      Ps[prow + 48 + l16] = (bf16)p3;
    }
#pragma unroll
    for (int n2 = 0; n2 < 16; ++n2) {
      f32x4 tv = o[n2];
      tv.x *= alpha_r[0]; tv.y *= alpha_r[1]; tv.z *= alpha_r[2]; tv.w *= alpha_r[3];
      o[n2] = tv;
    }
    __syncthreads();  // P visible (cross-lane through LDS)
    bf16x8 pf0 = *(const bf16x8*)(Ps + (wave * 16 + l16) * 72 + quad * 8);
    bf16x8 pf1 = *(const bf16x8*)(Ps + (wave * 16 + l16) * 72 + 32 + quad * 8);
#pragma unroll
    for (int n2 = 0; n2 < 16; ++n2) {
      bf16x8 vf0 = *(const bf16x8*)(Vs + (n2 * 16 + l16) * 72 + quad * 8);
      o[n2] = MFMA16(pf0, vf0, o[n2]);
      bf16x8 vf1 = *(const bf16x8*)(Vs + (n2 * 16 + l16) * 72 + 32 + quad * 8);
      o[n2] = MFMA16(pf1, vf1, o[n2]);
    }
  }
  float inv_l[4];
#pragma unroll
  for (int r = 0; r < 4; ++r) inv_l[r] = 1.0f / l_r[r];
  bf16* og = attn + ((long)(b * 1024 + qt * 64 + wave * 16 + quad * 4)) * 2048 +
             h * 256 + l16;
#pragma unroll
  for (int n2 = 0; n2 < 16; ++n2)
#pragma unroll
    for (int r = 0; r < 4; ++r)
      og[(long)r * 2048 + n2 * 16] = (bf16)(o[n2][r] * inv_l[r]);
}

extern "C" void kernel_launch(void* const* d_in, const int* in_sizes, int n_in,
                              void* d_out, int out_size, void* d_ws, size_t ws_size,
                              hipStream_t stream) {
  const float* x = (const float*)d_in[0];
  const float* k_cache = (const float*)d_in[1];
  const float* v_cache = (const float*)d_in[2];
  const float* wq = (const float*)d_in[3];
  const float* wk = (const float*)d_in[4];
  const float* wv = (const float*)d_in[5];
  const float* wo = (const float*)d_in[6];
  const float* qnw = (const float*)d_in[7];
  const float* knw = (const float*)d_in[8];
  const int* p_pos = (const int*)d_in[9];
  const int* p_ci = (const int*)d_in[10];

  float* out0 = (float*)d_out;                    // (2,1024,2560)
  float* kout = out0 + (long)2 * 1024 * 2560;     // (2,4,4096,256)
  float* vout = kout + (long)2 * 4 * 4096 * 256;  // (2,4,4096,256)

  char* w = (char*)d_ws;
  bf16* x_bf = (bf16*)(w);                  // 2048x2560 bf16        10,485,760 B
  bf16* wqkv_t = (bf16*)(w + 10485760);     // 4096x2560 bf16        20,971,520 B
  bf16* wo_t = (bf16*)(w + 31457280);       // 2560x2048 bf16        10,485,760 B
  float* qkv = (float*)(w + 41943040);      // 2048x4096 f32         33,554,432 B
  bf16* q_bf = (bf16*)(w + 75497472);       // (2,8,1024,256) bf16    8,388,608 B
  bf16* k_bf = (bf16*)(w + 83886080);       // (2,4,1024,256) bf16    4,194,304 B
  bf16* vt_bf = (bf16*)(w + 88080384);      // (2,4,256,1024) bf16    4,194,304 B
  bf16* attn_b = (bf16*)(w + 92274688);     // 2048x2048 bf16         8,388,608 B
                                            // total 100,663,296 B

  // 1. copy caches to outputs (new slice overwritten below, stream-ordered)
  hipMemcpyAsync(kout, k_cache, (size_t)8388608 * 4, hipMemcpyDeviceToDevice, stream);
  hipMemcpyAsync(vout, v_cache, (size_t)8388608 * 4, hipMemcpyDeviceToDevice, stream);

  // 2. dtype conversions / weight transposes
  cvt_x_kernel<<<5120, 256, 0, stream>>>(x, x_bf);
  dim3 tb(32, 8);
  wqkv_trans_kernel<<<dim3(80, 128), tb, 0, stream>>>(wq, wk, wv, wqkv_t);
  wo_trans_kernel<<<dim3(64, 80), tb, 0, stream>>>(wo, wo_t);

  // 3. fused QKV projection
  gemm_kernel<2560, 4096><<<dim3(16, 32), 256, 0, stream>>>(x_bf, wqkv_t, qkv);

  // 4. rmsnorm + rope + cache scatter (+ bf16 staging for attention)
  normrope_kernel<<<dim3(2048, 16), 256, 0, stream>>>(qkv, qnw, knw, p_pos, p_ci,
                                                      kout, vout, q_bf, k_bf);

  // 5. transpose new V slice for PV matmul
  v_trans_kernel<<<dim3(32, 8, 8), tb, 0, stream>>>(vout, p_ci, vt_bf);

  // 6. attention (window == T == 1024 new tokens, all valid, no causal mask)
  attn_kernel<<<dim3(16, 8, 2), 256, 0, stream>>>(q_bf, k_bf, vt_bf, attn_b);

  // 7. output projection
  gemm_kernel<2048, 2560><<<dim3(16, 20), 256, 0, stream>>>(attn_b, wo_t, out0);
}

// Round 3
// 420.594 us; speedup vs baseline: 1.0140x; 1.0140x over previous
//
#include <hip/hip_runtime.h>

typedef __bf16 bf16;
typedef __bf16 bf16x8 __attribute__((ext_vector_type(8)));
typedef __bf16 bf16x4 __attribute__((ext_vector_type(4)));
typedef float f32x4 __attribute__((ext_vector_type(4)));

#define MFMA16(a, b, c) __builtin_amdgcn_mfma_f32_16x16x32_bf16(a, b, c, 0, 0, 0)

// async global -> LDS, 16 B per lane. lds ptr must be WAVE-UNIFORM base;
// HW places lane i at base + i*16.
#define GLL(lds, g)                                                    \
  __builtin_amdgcn_global_load_lds(                                    \
      (const __attribute__((address_space(1))) void*)(g),              \
      (__attribute__((address_space(3))) void*)(lds), 16, 0, 0)

// ---------------- convert x (f32 -> bf16) ----------------
__global__ __launch_bounds__(256) void cvt_x_kernel(const float* __restrict__ x,
                                                    bf16* __restrict__ xb) {
  const long i = (long)blockIdx.x * 256 + threadIdx.x;  // one float4 per thread
  const float4 v = ((const float4*)x)[i];
  bf16x4 o4;
  o4.x = (bf16)v.x; o4.y = (bf16)v.y; o4.z = (bf16)v.z; o4.w = (bf16)v.w;
  ((bf16x4*)xb)[i] = o4;
}

// ---------------- transpose-convert [wq|wk|wv] (K x N) -> (N x K) bf16 ----------------
__global__ __launch_bounds__(256) void wqkv_trans_kernel(const float* __restrict__ wq,
                                                         const float* __restrict__ wk,
                                                         const float* __restrict__ wv,
                                                         bf16* __restrict__ dst) {
  __shared__ float tile[32][33];
  const int k0 = blockIdx.x * 32, n0 = blockIdx.y * 32;
  const float* src; int col, srcN;
  if (n0 < 2048)      { src = wq; col = n0;        srcN = 2048; }
  else if (n0 < 3072) { src = wk; col = n0 - 2048; srcN = 1024; }
  else                { src = wv; col = n0 - 3072; srcN = 1024; }
  const int tx = threadIdx.x, ty = threadIdx.y;  // 32 x 8
#pragma unroll
  for (int i = 0; i < 4; ++i)
    tile[ty + i * 8][tx] = src[(long)(k0 + ty + i * 8) * srcN + col + tx];
  __syncthreads();
#pragma unroll
  for (int i = 0; i < 4; ++i)
    dst[(long)(n0 + ty + i * 8) * 2560 + k0 + tx] = (bf16)tile[tx][ty + i * 8];
}

// ---------------- transpose-convert wo (2048 x 2560) -> (2560 x 2048) bf16 ----------------
__global__ __launch_bounds__(256) void wo_trans_kernel(const float* __restrict__ wo,
                                                       bf16* __restrict__ dst) {
  __shared__ float tile[32][33];
  const int k0 = blockIdx.x * 32, n0 = blockIdx.y * 32;
  const int tx = threadIdx.x, ty = threadIdx.y;
#pragma unroll
  for (int i = 0; i < 4; ++i)
    tile[ty + i * 8][tx] = wo[(long)(k0 + ty + i * 8) * 2560 + n0 + tx];
  __syncthreads();
#pragma unroll
  for (int i = 0; i < 4; ++i)
    dst[(long)(n0 + ty + i * 8) * 2048 + k0 + tx] = (bf16)tile[tx][ty + i * 8];
}

// ---------------- transpose new V slice (f32, [s][d]) -> vt bf16 [d][s] ----------------
__global__ __launch_bounds__(256) void v_trans_kernel(const float* __restrict__ vout,
                                                      const int* __restrict__ p_ci,
                                                      bf16* __restrict__ vt) {
  __shared__ float tile[32][33];
  const int s0 = blockIdx.x * 32, d0 = blockIdx.y * 32, bk = blockIdx.z;
  const int ci = *p_ci;
  const int tx = threadIdx.x, ty = threadIdx.y;
  const float* src = vout + ((long)bk * 4096 + ci) * 256;
#pragma unroll
  for (int i = 0; i < 4; ++i)
    tile[ty + i * 8][tx] = src[(long)(s0 + ty + i * 8) * 256 + d0 + tx];
  __syncthreads();
  bf16* dstb = vt + ((long)bk * 256 + d0) * 1024 + s0;
#pragma unroll
  for (int i = 0; i < 4; ++i)
    dstb[(long)(ty + i * 8) * 1024 + tx] = (bf16)tile[tx][ty + i * 8];
}

// ---------------- bf16 MFMA GEMM: C(f32, MxN) = A(MxK) * BT(NxK)^T ----------------
// BM=BN=128, BK=32, 256 threads = 4 waves; global_load_lds width-16 staging.
// LDS layout [row][32] unpadded with chunk swizzle cc_phys = (cc + (row>>1)) & 3
// -> frag ds_read_b128 hits all 8 bank-quads per 16-lane phase (conflict-free).
// Rows 64..127 start at ELEMENT offset 64*32 = 2048 (R2 bug was +4096: OOB).
template <int K, int N>
__global__ __launch_bounds__(256) void gemm_kernel(const bf16* __restrict__ A,
                                                   const bf16* __restrict__ BT,
                                                   float* __restrict__ C) {
  __shared__ bf16 As[128 * 32];
  __shared__ bf16 Bs[128 * 32];
  const int bm = blockIdx.x, bn = blockIdx.y;
  const int tid = threadIdx.x;
  const int wave = tid >> 6, lane = tid & 63;
  const int quad = lane >> 4, l16 = lane & 15;
  const int wm = (wave & 1) * 64, wn = (wave >> 1) * 64;
  f32x4 acc[4][4] = {};
  // staging: phys chunk index = tid (rows 0..63) and tid+256 (rows 64..127)
  const int r0 = tid >> 2;
  const int cc0 = ((tid & 3) - (r0 >> 1)) & 3;  // global chunk stored at phys slot
  const int r1 = r0 + 64;
  const int cc1 = ((tid & 3) - (r1 >> 1)) & 3;
  const bf16* Ag = A + (long)(bm * 128) * K;
  const bf16* Bg = BT + (long)(bn * 128) * K;
  bf16* AsW  = As + wave * 512;         // wave-uniform LDS bases (512 elem = 1 KiB)
  bf16* AsW2 = As + 2048 + wave * 512;  // rows 64..127 = element 64*32
  bf16* BsW  = Bs + wave * 512;
  bf16* BsW2 = Bs + 2048 + wave * 512;
  for (int k0 = 0; k0 < K; k0 += 32) {
    __syncthreads();  // previous iter's ds_reads done before overwrite
    GLL(AsW, Ag + (long)r0 * K + k0 + cc0 * 8);
    GLL(AsW2, Ag + (long)r1 * K + k0 + cc1 * 8);
    GLL(BsW, Bg + (long)r0 * K + k0 + cc0 * 8);
    GLL(BsW2, Bg + (long)r1 * K + k0 + cc1 * 8);
    __syncthreads();  // drains vmcnt -> staged data visible
    bf16x8 af[4], bfr[4];
#pragma unroll
    for (int mi = 0; mi < 4; ++mi) {
      const int r = wm + mi * 16 + l16;
      af[mi] = *(const bf16x8*)(As + r * 32 + (((quad + (r >> 1)) & 3) * 8));
    }
#pragma unroll
    for (int ni = 0; ni < 4; ++ni) {
      const int r = wn + ni * 16 + l16;
      bfr[ni] = *(const bf16x8*)(Bs + r * 32 + (((quad + (r >> 1)) & 3) * 8));
    }
#pragma unroll
    for (int mi = 0; mi < 4; ++mi)
#pragma unroll
      for (int ni = 0; ni < 4; ++ni)
        acc[mi][ni] = MFMA16(af[mi], bfr[ni], acc[mi][ni]);
  }
  const int crow = bm * 128 + wm + quad * 4;
  const int ccol = bn * 128 + wn + l16;
#pragma unroll
  for (int mi = 0; mi < 4; ++mi)
#pragma unroll
    for (int ni = 0; ni < 4; ++ni)
#pragma unroll
      for (int r = 0; r < 4; ++r)
        C[(long)(crow + mi * 16 + r) * N + ccol + ni * 16] = acc[mi][ni][r];
}

// ---------------- RMSNorm + RoPE + cache scatter ----------------
__global__ __launch_bounds__(256) void normrope_kernel(
    const float* __restrict__ qkv, const float* __restrict__ qw,
    const float* __restrict__ kw, const int* __restrict__ p_pos,
    const int* __restrict__ p_ci, float* __restrict__ kout,
    float* __restrict__ vout, bf16* __restrict__ q_bf, bf16* __restrict__ k_bf) {
  const int bt = blockIdx.x, slot = blockIdx.y;
  const int t = bt & 1023, b = bt >> 10;
  const int d = threadIdx.x;
  const float val = qkv[(long)bt * 4096 + slot * 256 + d];
  const int ci = *p_ci;
  if (slot >= 12) {  // v: plain scatter into cache
    vout[((long)(b * 4 + (slot - 12)) * 4096 + ci + t) * 256 + d] = val;
    return;
  }
  __shared__ float red[4];
  __shared__ float rowbuf[256];
  float ss = val * val;
#pragma unroll
  for (int i = 1; i < 64; i <<= 1) ss += __shfl_xor(ss, i);
  if ((d & 63) == 0) red[d >> 6] = ss;
  __syncthreads();
  const float tot = red[0] + red[1] + red[2] + red[3];
  const float rstd = rsqrtf(tot * (1.0f / 256.0f) + 1e-6f);
  const bool isq = slot < 8;
  const float wv = isq ? qw[d] : kw[d];
  const float nv = val * rstd * (1.0f + wv);
  rowbuf[d] = nv;
  __syncthreads();
  const int e = d & 127;
  const float inv_freq = exp2f((float)e * -0.10381025296522976f);
  const float ang = (float)(*p_pos + t) * inv_freq;
  float sn, cs;
  sincosf(ang, &sn, &cs);
  float outv;
  if (d < 128) outv = nv * cs - rowbuf[d + 128] * sn;
  else         outv = nv * cs + rowbuf[d - 128] * sn;
  if (isq) {
    q_bf[((long)(b * 8 + slot) * 1024 + t) * 256 + d] = (bf16)outv;
  } else {
    const int kh = slot - 8;
    kout[((long)(b * 4 + kh) * 4096 + ci + t) * 256 + d] = outv;
    k_bf[((long)(b * 4 + kh) * 1024 + t) * 256 + d] = (bf16)outv;
  }
}

// ---------------- flash attention over the T new tokens (all valid, no mask) ----
// grid (16 q-tiles, 8 heads, 2 batch); 4 waves; wave owns 16 query rows.
// K/V staged via global_load_lds with XOR chunk swizzle: phys slot p of row r
// holds global chunk p ^ (r&7); frag read fetches (logical ^ (r&7)).
__global__ __launch_bounds__(256) void attn_kernel(const bf16* __restrict__ q_bf,
                                                   const bf16* __restrict__ k_bf,
                                                   const bf16* __restrict__ vt_bf,
                                                   bf16* __restrict__ attn) {
  __shared__ bf16 Ks[64 * 256];   // [s][d], chunk-swizzled
  __shared__ bf16 Vs[256 * 64];   // [d][s], chunk-swizzled
  __shared__ bf16 Ps[64 * 72];    // [t][s], +8 pad (VALU-written)
  const int qt = blockIdx.x, h = blockIdx.y, b = blockIdx.z;
  const int kvh = h >> 1;
  const int tid = threadIdx.x;
  const int wave = tid >> 6, lane = tid & 63, quad = lane >> 4, l16 = lane & 15;
  bf16x8 qf[8];
  const bf16* qg =
      q_bf + ((long)(b * 8 + h) * 1024 + qt * 64 + wave * 16 + l16) * 256 + quad * 8;
#pragma unroll
  for (int i = 0; i < 8; ++i) qf[i] = *(const bf16x8*)(qg + i * 32);
  f32x4 o[16] = {};
  float m_r[4] = {-1e30f, -1e30f, -1e30f, -1e30f};
  float l_r[4] = {0.f, 0.f, 0.f, 0.f};
  const float sfac = 0.0625f * 1.44269504088896f;  // SCALE * log2(e)
  const bf16* kgb = k_bf + (long)(b * 4 + kvh) * 1024 * 256;
  const bf16* vgb = vt_bf + (long)(b * 4 + kvh) * 256 * 1024;
  // staging decode for K: phys chunk = i*256 + tid -> row = i*8 + (tid>>5)
  const int krow = tid >> 5, kccp = tid & 31;
  const int kcc = kccp ^ (krow & 7);
  // staging decode for V: phys chunk = i*256 + tid -> row = i*32 + (tid>>3)
  const int vrow0 = tid >> 3, vccp = tid & 7;
  for (int st = 0; st < 16; ++st) {
    __syncthreads();  // previous iter's ds_reads done
#pragma unroll
    for (int i = 0; i < 8; ++i) {  // K tile 64x256: rows krow + i*8
      GLL(Ks + (i * 256 + wave * 64) * 8,
          kgb + (long)(st * 64 + krow + i * 8) * 256 + kcc * 8);
    }
#pragma unroll
    for (int i = 0; i < 8; ++i) {  // V^T tile 256x64: rows vrow0 + i*32
      const int vr = vrow0 + i * 32;
      GLL(Vs + (i * 256 + wave * 64) * 8,
          vgb + (long)vr * 1024 + st * 64 + (vccp ^ (vr & 7)) * 8);
    }
    __syncthreads();  // drains vmcnt -> tiles visible
    // S = Q K^T
    f32x4 sacc[4] = {};
#pragma unroll
    for (int kk = 0; kk < 8; ++kk) {
#pragma unroll
      for (int ni = 0; ni < 4; ++ni) {
        const int r = ni * 16 + l16;
        bf16x8 kf = *(const bf16x8*)(Ks + r * 256 + (((kk * 4 + quad) ^ (r & 7)) * 8));
        sacc[ni] = MFMA16(qf[kk], kf, sacc[ni]);
      }
    }
    float alpha_r[4];
#pragma unroll
    for (int r = 0; r < 4; ++r) {
      float s0 = sacc[0][r] * sfac, s1 = sacc[1][r] * sfac;
      float s2 = sacc[2][r] * sfac, s3 = sacc[3][r] * sfac;
      float mx = fmaxf(fmaxf(s0, s1), fmaxf(s2, s3));
#pragma unroll
      for (int dd = 1; dd < 16; dd <<= 1) mx = fmaxf(mx, __shfl_xor(mx, dd));
      float mnew = fmaxf(m_r[r], mx);
      float al = exp2f(m_r[r] - mnew);
      m_r[r] = mnew;
      alpha_r[r] = al;
      float p0 = exp2f(s0 - mnew), p1 = exp2f(s1 - mnew);
      float p2 = exp2f(s2 - mnew), p3 = exp2f(s3 - mnew);
      float rs = p0 + p1 + p2 + p3;
#pragma unroll
      for (int dd = 1; dd < 16; dd <<= 1) rs += __shfl_xor(rs, dd);
      l_r[r] = l_r[r] * al + rs;
      const int prow = (wave * 16 + quad * 4 + r) * 72;
      Ps[prow + l16] = (bf16)p0;
      Ps[prow + 16 + l16] = (bf16)p1;
      Ps[prow + 32 + l16] = (bf16)p2;
      Ps[prow + 48 + l16] = (bf16)p3;
    }
#pragma unroll
    for (int n2 = 0; n2 < 16; ++n2) {
      f32x4 tv = o[n2];
      tv.x *= alpha_r[0]; tv.y *= alpha_r[1]; tv.z *= alpha_r[2]; tv.w *= alpha_r[3];
      o[n2] = tv;
    }
    __syncthreads();  // P visible
    bf16x8 pf0 = *(const bf16x8*)(Ps + (wave * 16 + l16) * 72 + quad * 8);
    bf16x8 pf1 = *(const bf16x8*)(Ps + (wave * 16 + l16) * 72 + 32 + quad * 8);
#pragma unroll
    for (int n2 = 0; n2 < 16; ++n2) {
      const int r = n2 * 16 + l16;
      bf16x8 vf0 = *(const bf16x8*)(Vs + r * 64 + ((quad ^ (r & 7)) * 8));
      o[n2] = MFMA16(pf0, vf0, o[n2]);
      bf16x8 vf1 = *(const bf16x8*)(Vs + r * 64 + (((4 + quad) ^ (r & 7)) * 8));
      o[n2] = MFMA16(pf1, vf1, o[n2]);
    }
  }
  float inv_l[4];
#pragma unroll
  for (int r = 0; r < 4; ++r) inv_l[r] = 1.0f / l_r[r];
  bf16* og = attn + ((long)(b * 1024 + qt * 64 + wave * 16 + quad * 4)) * 2048 +
             h * 256 + l16;
#pragma unroll
  for (int n2 = 0; n2 < 16; ++n2)
#pragma unroll
    for (int r = 0; r < 4; ++r)
      og[(long)r * 2048 + n2 * 16] = (bf16)(o[n2][r] * inv_l[r]);
}

extern "C" void kernel_launch(void* const* d_in, const int* in_sizes, int n_in,
                              void* d_out, int out_size, void* d_ws, size_t ws_size,
                              hipStream_t stream) {
  const float* x = (const float*)d_in[0];
  const float* k_cache = (const float*)d_in[1];
  const float* v_cache = (const float*)d_in[2];
  const float* wq = (const float*)d_in[3];
  const float* wk = (const float*)d_in[4];
  const float* wv = (const float*)d_in[5];
  const float* wo = (const float*)d_in[6];
  const float* qnw = (const float*)d_in[7];
  const float* knw = (const float*)d_in[8];
  const int* p_pos = (const int*)d_in[9];
  const int* p_ci = (const int*)d_in[10];

  float* out0 = (float*)d_out;                    // (2,1024,2560)
  float* kout = out0 + (long)2 * 1024 * 2560;     // (2,4,4096,256)
  float* vout = kout + (long)2 * 4 * 4096 * 256;  // (2,4,4096,256)

  char* w = (char*)d_ws;
  bf16* x_bf = (bf16*)(w);                  // 2048x2560 bf16        10,485,760 B
  bf16* wqkv_t = (bf16*)(w + 10485760);     // 4096x2560 bf16        20,971,520 B
  bf16* wo_t = (bf16*)(w + 31457280);       // 2560x2048 bf16        10,485,760 B
  float* qkv = (float*)(w + 41943040);      // 2048x4096 f32         33,554,432 B
  bf16* q_bf = (bf16*)(w + 75497472);       // (2,8,1024,256) bf16    8,388,608 B
  bf16* k_bf = (bf16*)(w + 83886080);       // (2,4,1024,256) bf16    4,194,304 B
  bf16* vt_bf = (bf16*)(w + 88080384);      // (2,4,256,1024) bf16    4,194,304 B
  bf16* attn_b = (bf16*)(w + 92274688);     // 2048x2048 bf16         8,388,608 B

  hipMemcpyAsync(kout, k_cache, (size_t)8388608 * 4, hipMemcpyDeviceToDevice, stream);
  hipMemcpyAsync(vout, v_cache, (size_t)8388608 * 4, hipMemcpyDeviceToDevice, stream);

  cvt_x_kernel<<<5120, 256, 0, stream>>>(x, x_bf);
  dim3 tb(32, 8);
  wqkv_trans_kernel<<<dim3(80, 128), tb, 0, stream>>>(wq, wk, wv, wqkv_t);
  wo_trans_kernel<<<dim3(64, 80), tb, 0, stream>>>(wo, wo_t);

  gemm_kernel<2560, 4096><<<dim3(16, 32), 256, 0, stream>>>(x_bf, wqkv_t, qkv);

  normrope_kernel<<<dim3(2048, 16), 256, 0, stream>>>(qkv, qnw, knw, p_pos, p_ci,
                                                      kout, vout, q_bf, k_bf);

  v_trans_kernel<<<dim3(32, 8, 8), tb, 0, stream>>>(vout, p_ci, vt_bf);

  attn_kernel<<<dim3(16, 8, 2), 256, 0, stream>>>(q_bf, k_bf, vt_bf, attn_b);

  gemm_kernel<2048, 2560><<<dim3(16, 20), 256, 0, stream>>>(attn_b, wo_t, out0);
}

// Round 4
// 395.451 us; speedup vs baseline: 1.0784x; 1.0636x over previous
//
#include <hip/hip_runtime.h>

typedef __bf16 bf16;
typedef __bf16 bf16x8 __attribute__((ext_vector_type(8)));
typedef __bf16 bf16x4 __attribute__((ext_vector_type(4)));
typedef float f32x4 __attribute__((ext_vector_type(4)));

#define MFMA16(a, b, c) __builtin_amdgcn_mfma_f32_16x16x32_bf16(a, b, c, 0, 0, 0)

// async global -> LDS, 16 B per lane. lds ptr must be WAVE-UNIFORM base;
// HW places lane i at base + i*16.
#define GLL(lds, g)                                                    \
  __builtin_amdgcn_global_load_lds(                                    \
      (const __attribute__((address_space(1))) void*)(g),              \
      (__attribute__((address_space(3))) void*)(lds), 16, 0, 0)

// ---------------- cache copy (replaces SDMA memcpy nodes) ----------------
// Copies k_cache/v_cache -> kout/vout EXCEPT s in [ci, ci+1024) which
// normrope/v-scatter overwrite. One wave handles one 256-f32 row as float4.
__global__ __launch_bounds__(256) void cache_copy_kernel(
    const float* __restrict__ kc, const float* __restrict__ vc,
    float* __restrict__ kout, float* __restrict__ vout,
    const int* __restrict__ p_ci) {
  const int s = blockIdx.x * 4 + (threadIdx.x >> 6);  // 0..4095
  const int bk = blockIdx.y;                          // 0..7
  const int ci = *p_ci;
  if ((unsigned)(s - ci) < 1024u) return;  // overwritten slice, skip (wave-uniform)
  const long base = ((long)bk * 4096 + s) * 64 + (threadIdx.x & 63);
  ((float4*)kout)[base] = ((const float4*)kc)[base];
  ((float4*)vout)[base] = ((const float4*)vc)[base];
}

// ---------------- convert x (f32 -> bf16) ----------------
__global__ __launch_bounds__(256) void cvt_x_kernel(const float* __restrict__ x,
                                                    bf16* __restrict__ xb) {
  const long i = (long)blockIdx.x * 256 + threadIdx.x;  // one float4 per thread
  const float4 v = ((const float4*)x)[i];
  bf16x4 o4;
  o4.x = (bf16)v.x; o4.y = (bf16)v.y; o4.z = (bf16)v.z; o4.w = (bf16)v.w;
  ((bf16x4*)xb)[i] = o4;
}

// ---------------- transpose-convert [wq|wk|wv] (K x N) -> (N x K) bf16 ----------------
__global__ __launch_bounds__(256) void wqkv_trans_kernel(const float* __restrict__ wq,
                                                         const float* __restrict__ wk,
                                                         const float* __restrict__ wv,
                                                         bf16* __restrict__ dst) {
  __shared__ float tile[32][33];
  const int k0 = blockIdx.x * 32, n0 = blockIdx.y * 32;
  const float* src; int col, srcN;
  if (n0 < 2048)      { src = wq; col = n0;        srcN = 2048; }
  else if (n0 < 3072) { src = wk; col = n0 - 2048; srcN = 1024; }
  else                { src = wv; col = n0 - 3072; srcN = 1024; }
  const int tx = threadIdx.x, ty = threadIdx.y;  // 32 x 8
#pragma unroll
  for (int i = 0; i < 4; ++i)
    tile[ty + i * 8][tx] = src[(long)(k0 + ty + i * 8) * srcN + col + tx];
  __syncthreads();
#pragma unroll
  for (int i = 0; i < 4; ++i)
    dst[(long)(n0 + ty + i * 8) * 2560 + k0 + tx] = (bf16)tile[tx][ty + i * 8];
}

// ---------------- transpose-convert wo (2048 x 2560) -> (2560 x 2048) bf16 ----------------
__global__ __launch_bounds__(256) void wo_trans_kernel(const float* __restrict__ wo,
                                                       bf16* __restrict__ dst) {
  __shared__ float tile[32][33];
  const int k0 = blockIdx.x * 32, n0 = blockIdx.y * 32;
  const int tx = threadIdx.x, ty = threadIdx.y;
#pragma unroll
  for (int i = 0; i < 4; ++i)
    tile[ty + i * 8][tx] = wo[(long)(k0 + ty + i * 8) * 2560 + n0 + tx];
  __syncthreads();
#pragma unroll
  for (int i = 0; i < 4; ++i)
    dst[(long)(n0 + ty + i * 8) * 2048 + k0 + tx] = (bf16)tile[tx][ty + i * 8];
}

// ---------------- transpose new V slice (f32, [s][d]) -> vt bf16 [d][s] ----------------
__global__ __launch_bounds__(256) void v_trans_kernel(const float* __restrict__ vout,
                                                      const int* __restrict__ p_ci,
                                                      bf16* __restrict__ vt) {
  __shared__ float tile[32][33];
  const int s0 = blockIdx.x * 32, d0 = blockIdx.y * 32, bk = blockIdx.z;
  const int ci = *p_ci;
  const int tx = threadIdx.x, ty = threadIdx.y;
  const float* src = vout + ((long)bk * 4096 + ci) * 256;
#pragma unroll
  for (int i = 0; i < 4; ++i)
    tile[ty + i * 8][tx] = src[(long)(s0 + ty + i * 8) * 256 + d0 + tx];
  __syncthreads();
  bf16* dstb = vt + ((long)bk * 256 + d0) * 1024 + s0;
#pragma unroll
  for (int i = 0; i < 4; ++i)
    dstb[(long)(ty + i * 8) * 1024 + tx] = (bf16)tile[tx][ty + i * 8];
}

// ---------------- bf16 MFMA GEMM: C(f32, MxN) = A(MxK) * BT(NxK)^T ----------------
// R4: BM=128, BN=64, BK=64 -> QKV grid 16x64 = 1024 blocks (4/CU, was 2/CU).
// 4 waves, each owns 64x32 (4x2 subtiles). global_load_lds width-16 staging.
// Row = 64 elems = 8 chunks of 16B; XOR swizzle phys = c ^ (row&7):
// frag reads worst-case 2-way bank alias (free per m136); staging reads
// stay within each row's contiguous 128 B (coalesced).
template <int K, int N>
__global__ __launch_bounds__(256) void gemm_kernel(const bf16* __restrict__ A,
                                                   const bf16* __restrict__ BT,
                                                   float* __restrict__ C) {
  __shared__ bf16 As[128 * 64];  // 16 KiB
  __shared__ bf16 Bs[64 * 64];   //  8 KiB
  const int bm = blockIdx.x, bn = blockIdx.y;
  const int tid = threadIdx.x;
  const int wave = tid >> 6, lane = tid & 63;
  const int quad = lane >> 4, l16 = lane & 15;
  const int wm = (wave & 1) * 64, wn = (wave >> 1) * 32;
  f32x4 acc[4][2] = {};
  // staging decode: phys chunk p = i*256 + tid; row = p>>3; gcol = (p&7) ^ (row&7)
  const int srow = tid >> 3;   // + i*32
  const int scol = tid & 7;
  const bf16* Ag = A + (long)(bm * 128) * K;
  const bf16* Bg = BT + (long)(bn * 64) * K;
  for (int k0 = 0; k0 < K; k0 += 64) {
    __syncthreads();  // previous iter's ds_reads done before overwrite
#pragma unroll
    for (int i = 0; i < 4; ++i) {  // A: 128 rows x 8 chunks = 1024 chunks
      const int r = i * 32 + srow;
      GLL(As + (i * 256 + wave * 64) * 8, Ag + (long)r * K + k0 + (scol ^ (r & 7)) * 8);
    }
#pragma unroll
    for (int i = 0; i < 2; ++i) {  // B: 64 rows x 8 chunks = 512 chunks
      const int r = i * 32 + srow;
      GLL(Bs + (i * 256 + wave * 64) * 8, Bg + (long)r * K + k0 + (scol ^ (r & 7)) * 8);
    }
    __syncthreads();  // drains vmcnt -> staged data visible
#pragma unroll
    for (int kk = 0; kk < 2; ++kk) {
      bf16x8 af[4], bfr[2];
#pragma unroll
      for (int mi = 0; mi < 4; ++mi) {
        const int r = wm + mi * 16 + l16;
        af[mi] = *(const bf16x8*)(As + r * 64 + (((kk * 4 + quad) ^ (r & 7)) * 8));
      }
#pragma unroll
      for (int ni = 0; ni < 2; ++ni) {
        const int r = wn + ni * 16 + l16;
        bfr[ni] = *(const bf16x8*)(Bs + r * 64 + (((kk * 4 + quad) ^ (r & 7)) * 8));
      }
#pragma unroll
      for (int mi = 0; mi < 4; ++mi)
#pragma unroll
        for (int ni = 0; ni < 2; ++ni)
          acc[mi][ni] = MFMA16(af[mi], bfr[ni], acc[mi][ni]);
    }
  }
  const int crow = bm * 128 + wm + quad * 4;
  const int ccol = bn * 64 + wn + l16;
#pragma unroll
  for (int mi = 0; mi < 4; ++mi)
#pragma unroll
    for (int ni = 0; ni < 2; ++ni)
#pragma unroll
      for (int r = 0; r < 4; ++r)
        C[(long)(crow + mi * 16 + r) * N + ccol + ni * 16] = acc[mi][ni][r];
}

// ---------------- RMSNorm + RoPE + cache scatter ----------------
__global__ __launch_bounds__(256) void normrope_kernel(
    const float* __restrict__ qkv, const float* __restrict__ qw,
    const float* __restrict__ kw, const int* __restrict__ p_pos,
    const int* __restrict__ p_ci, float* __restrict__ kout,
    float* __restrict__ vout, bf16* __restrict__ q_bf, bf16* __restrict__ k_bf) {
  const int bt = blockIdx.x, slot = blockIdx.y;
  const int t = bt & 1023, b = bt >> 10;
  const int d = threadIdx.x;
  const float val = qkv[(long)bt * 4096 + slot * 256 + d];
  const int ci = *p_ci;
  if (slot >= 12) {  // v: plain scatter into cache
    vout[((long)(b * 4 + (slot - 12)) * 4096 + ci + t) * 256 + d] = val;
    return;
  }
  __shared__ float red[4];
  __shared__ float rowbuf[256];
  float ss = val * val;
#pragma unroll
  for (int i = 1; i < 64; i <<= 1) ss += __shfl_xor(ss, i);
  if ((d & 63) == 0) red[d >> 6] = ss;
  __syncthreads();
  const float tot = red[0] + red[1] + red[2] + red[3];
  const float rstd = rsqrtf(tot * (1.0f / 256.0f) + 1e-6f);
  const bool isq = slot < 8;
  const float wv = isq ? qw[d] : kw[d];
  const float nv = val * rstd * (1.0f + wv);
  rowbuf[d] = nv;
  __syncthreads();
  const int e = d & 127;
  const float inv_freq = exp2f((float)e * -0.10381025296522976f);
  const float ang = (float)(*p_pos + t) * inv_freq;
  float sn, cs;
  sincosf(ang, &sn, &cs);
  float outv;
  if (d < 128) outv = nv * cs - rowbuf[d + 128] * sn;
  else         outv = nv * cs + rowbuf[d - 128] * sn;
  if (isq) {
    q_bf[((long)(b * 8 + slot) * 1024 + t) * 256 + d] = (bf16)outv;
  } else {
    const int kh = slot - 8;
    kout[((long)(b * 4 + kh) * 4096 + ci + t) * 256 + d] = outv;
    k_bf[((long)(b * 4 + kh) * 1024 + t) * 256 + d] = (bf16)outv;
  }
}

// ---------------- flash attention over the T new tokens (all valid, no mask) ----
__global__ __launch_bounds__(256) void attn_kernel(const bf16* __restrict__ q_bf,
                                                   const bf16* __restrict__ k_bf,
                                                   const bf16* __restrict__ vt_bf,
                                                   bf16* __restrict__ attn) {
  __shared__ bf16 Ks[64 * 256];   // [s][d], chunk-swizzled
  __shared__ bf16 Vs[256 * 64];   // [d][s], chunk-swizzled
  __shared__ bf16 Ps[64 * 72];    // [t][s], +8 pad (VALU-written)
  const int qt = blockIdx.x, h = blockIdx.y, b = blockIdx.z;
  const int kvh = h >> 1;
  const int tid = threadIdx.x;
  const int wave = tid >> 6, lane = tid & 63, quad = lane >> 4, l16 = lane & 15;
  bf16x8 qf[8];
  const bf16* qg =
      q_bf + ((long)(b * 8 + h) * 1024 + qt * 64 + wave * 16 + l16) * 256 + quad * 8;
#pragma unroll
  for (int i = 0; i < 8; ++i) qf[i] = *(const bf16x8*)(qg + i * 32);
  f32x4 o[16] = {};
  float m_r[4] = {-1e30f, -1e30f, -1e30f, -1e30f};
  float l_r[4] = {0.f, 0.f, 0.f, 0.f};
  const float sfac = 0.0625f * 1.44269504088896f;  // SCALE * log2(e)
  const bf16* kgb = k_bf + (long)(b * 4 + kvh) * 1024 * 256;
  const bf16* vgb = vt_bf + (long)(b * 4 + kvh) * 256 * 1024;
  const int krow = tid >> 5, kccp = tid & 31;
  const int kcc = kccp ^ (krow & 7);
  const int vrow0 = tid >> 3, vccp = tid & 7;
  for (int st = 0; st < 16; ++st) {
    __syncthreads();  // previous iter's ds_reads done
#pragma unroll
    for (int i = 0; i < 8; ++i) {  // K tile 64x256: rows krow + i*8
      GLL(Ks + (i * 256 + wave * 64) * 8,
          kgb + (long)(st * 64 + krow + i * 8) * 256 + kcc * 8);
    }
#pragma unroll
    for (int i = 0; i < 8; ++i) {  // V^T tile 256x64: rows vrow0 + i*32
      const int vr = vrow0 + i * 32;
      GLL(Vs + (i * 256 + wave * 64) * 8,
          vgb + (long)vr * 1024 + st * 64 + (vccp ^ (vr & 7)) * 8);
    }
    __syncthreads();  // drains vmcnt -> tiles visible
    f32x4 sacc[4] = {};
#pragma unroll
    for (int kk = 0; kk < 8; ++kk) {
#pragma unroll
      for (int ni = 0; ni < 4; ++ni) {
        const int r = ni * 16 + l16;
        bf16x8 kf = *(const bf16x8*)(Ks + r * 256 + (((kk * 4 + quad) ^ (r & 7)) * 8));
        sacc[ni] = MFMA16(qf[kk], kf, sacc[ni]);
      }
    }
    float alpha_r[4];
#pragma unroll
    for (int r = 0; r < 4; ++r) {
      float s0 = sacc[0][r] * sfac, s1 = sacc[1][r] * sfac;
      float s2 = sacc[2][r] * sfac, s3 = sacc[3][r] * sfac;
      float mx = fmaxf(fmaxf(s0, s1), fmaxf(s2, s3));
#pragma unroll
      for (int dd = 1; dd < 16; dd <<= 1) mx = fmaxf(mx, __shfl_xor(mx, dd));
      float mnew = fmaxf(m_r[r], mx);
      float al = exp2f(m_r[r] - mnew);
      m_r[r] = mnew;
      alpha_r[r] = al;
      float p0 = exp2f(s0 - mnew), p1 = exp2f(s1 - mnew);
      float p2 = exp2f(s2 - mnew), p3 = exp2f(s3 - mnew);
      float rs = p0 + p1 + p2 + p3;
#pragma unroll
      for (int dd = 1; dd < 16; dd <<= 1) rs += __shfl_xor(rs, dd);
      l_r[r] = l_r[r] * al + rs;
      const int prow = (wave * 16 + quad * 4 + r) * 72;
      Ps[prow + l16] = (bf16)p0;
      Ps[prow + 16 + l16] = (bf16)p1;
      Ps[prow + 32 + l16] = (bf16)p2;
      Ps[prow + 48 + l16] = (bf16)p3;
    }
#pragma unroll
    for (int n2 = 0; n2 < 16; ++n2) {
      f32x4 tv = o[n2];
      tv.x *= alpha_r[0]; tv.y *= alpha_r[1]; tv.z *= alpha_r[2]; tv.w *= alpha_r[3];
      o[n2] = tv;
    }
    __syncthreads();  // P visible
    bf16x8 pf0 = *(const bf16x8*)(Ps + (wave * 16 + l16) * 72 + quad * 8);
    bf16x8 pf1 = *(const bf16x8*)(Ps + (wave * 16 + l16) * 72 + 32 + quad * 8);
#pragma unroll
    for (int n2 = 0; n2 < 16; ++n2) {
      const int r = n2 * 16 + l16;
      bf16x8 vf0 = *(const bf16x8*)(Vs + r * 64 + ((quad ^ (r & 7)) * 8));
      o[n2] = MFMA16(pf0, vf0, o[n2]);
      bf16x8 vf1 = *(const bf16x8*)(Vs + r * 64 + (((4 + quad) ^ (r & 7)) * 8));
      o[n2] = MFMA16(pf1, vf1, o[n2]);
    }
  }
  float inv_l[4];
#pragma unroll
  for (int r = 0; r < 4; ++r) inv_l[r] = 1.0f / l_r[r];
  bf16* og = attn + ((long)(b * 1024 + qt * 64 + wave * 16 + quad * 4)) * 2048 +
             h * 256 + l16;
#pragma unroll
  for (int n2 = 0; n2 < 16; ++n2)
#pragma unroll
    for (int r = 0; r < 4; ++r)
      og[(long)r * 2048 + n2 * 16] = (bf16)(o[n2][r] * inv_l[r]);
}

extern "C" void kernel_launch(void* const* d_in, const int* in_sizes, int n_in,
                              void* d_out, int out_size, void* d_ws, size_t ws_size,
                              hipStream_t stream) {
  const float* x = (const float*)d_in[0];
  const float* k_cache = (const float*)d_in[1];
  const float* v_cache = (const float*)d_in[2];
  const float* wq = (const float*)d_in[3];
  const float* wk = (const float*)d_in[4];
  const float* wv = (const float*)d_in[5];
  const float* wo = (const float*)d_in[6];
  const float* qnw = (const float*)d_in[7];
  const float* knw = (const float*)d_in[8];
  const int* p_pos = (const int*)d_in[9];
  const int* p_ci = (const int*)d_in[10];

  float* out0 = (float*)d_out;                    // (2,1024,2560)
  float* kout = out0 + (long)2 * 1024 * 2560;     // (2,4,4096,256)
  float* vout = kout + (long)2 * 4 * 4096 * 256;  // (2,4,4096,256)

  char* w = (char*)d_ws;
  bf16* x_bf = (bf16*)(w);                  // 2048x2560 bf16        10,485,760 B
  bf16* wqkv_t = (bf16*)(w + 10485760);     // 4096x2560 bf16        20,971,520 B
  bf16* wo_t = (bf16*)(w + 31457280);       // 2560x2048 bf16        10,485,760 B
  float* qkv = (float*)(w + 41943040);      // 2048x4096 f32         33,554,432 B
  bf16* q_bf = (bf16*)(w + 75497472);       // (2,8,1024,256) bf16    8,388,608 B
  bf16* k_bf = (bf16*)(w + 83886080);       // (2,4,1024,256) bf16    4,194,304 B
  bf16* vt_bf = (bf16*)(w + 88080384);      // (2,4,256,1024) bf16    4,194,304 B
  bf16* attn_b = (bf16*)(w + 92274688);     // 2048x2048 bf16         8,388,608 B

  // 1. cache copy as a kernel (SDMA memcpy nodes were invisible & likely slow);
  //    skips the [ci, ci+1024) slice that gets overwritten below.
  cache_copy_kernel<<<dim3(1024, 8), 256, 0, stream>>>(k_cache, v_cache, kout,
                                                       vout, p_ci);

  // 2. dtype conversions / weight transposes
  cvt_x_kernel<<<5120, 256, 0, stream>>>(x, x_bf);
  dim3 tb(32, 8);
  wqkv_trans_kernel<<<dim3(80, 128), tb, 0, stream>>>(wq, wk, wv, wqkv_t);
  wo_trans_kernel<<<dim3(64, 80), tb, 0, stream>>>(wo, wo_t);

  // 3. fused QKV projection — 128x64 tiles, 1024 blocks (4/CU)
  gemm_kernel<2560, 4096><<<dim3(16, 64), 256, 0, stream>>>(x_bf, wqkv_t, qkv);

  // 4. rmsnorm + rope + cache scatter
  normrope_kernel<<<dim3(2048, 16), 256, 0, stream>>>(qkv, qnw, knw, p_pos, p_ci,
                                                      kout, vout, q_bf, k_bf);

  // 5. transpose new V slice for PV matmul
  v_trans_kernel<<<dim3(32, 8, 8), tb, 0, stream>>>(vout, p_ci, vt_bf);

  // 6. attention
  attn_kernel<<<dim3(16, 8, 2), 256, 0, stream>>>(q_bf, k_bf, vt_bf, attn_b);

  // 7. output projection — 128x64 tiles, 640 blocks (2.5/CU)
  gemm_kernel<2048, 2560><<<dim3(16, 40), 256, 0, stream>>>(attn_b, wo_t, out0);
}